// Round 5
// baseline (822.761 us; speedup 1.0000x reference)
//
#include <hip/hip_runtime.h>
#include <hip/hip_bf16.h>

typedef unsigned short u16;
typedef unsigned int u32;
typedef unsigned long long u64;

#define LSEQ 256

// ---------------- ws float-offsets ----------------
constexpr int XW_F  = 0;        // [b][t][1024] fp32 (x@W + b), fwd
constexpr int XW_B  = 524288;   // bwd
constexpr int HF_O  = 1048576;  // hstep_f [s][k] -> (f32 b0, f32 b1) u64 pairs
constexpr int HB_O  = 1179648;  // hstep_b [s][k] pairs (s = step, t_orig = 255-s)
constexpr int PEH_O = 1703936;  // [512]
constexpr int QEH_O = 1704448;  // [512]
constexpr int PHH_O = 1704960;  // [512][24]
constexpr int QHH_O = 1717248;
constexpr int PTT_O = 1729536;
constexpr int QTT_O = 1741824;

constexpr u64 SENT64 = 0x7FC000007FC00000ULL;  // (qNaN,qNaN) fp32 pair

__device__ __forceinline__ float b2f(u16 u) {
  u32 x = ((u32)u) << 16; float f;
  __builtin_memcpy(&f, &x, 4); return f;
}
__device__ __forceinline__ u16 f2b(float f) {
  u32 x; __builtin_memcpy(&x, &f, 4);
  u32 r = (x + 0x7fffu + ((x >> 16) & 1u)) >> 16;
  return (u16)r;
}
__device__ __forceinline__ float sigm(float x) {
  return __builtin_amdgcn_rcpf(1.f + __expf(-x));
}
__device__ __forceinline__ float tanh_fast(float x) {
  return 2.f * __builtin_amdgcn_rcpf(1.f + __expf(-2.f * x)) - 1.f;
}
__device__ __forceinline__ u64 aload64(u64* p) {
  return __hip_atomic_load(p, __ATOMIC_RELAXED, __HIP_MEMORY_SCOPE_AGENT);
}
__device__ __forceinline__ void astore64(u64* p, u64 v) {
  __hip_atomic_store(p, v, __ATOMIC_RELAXED, __HIP_MEMORY_SCOPE_AGENT);
}
// dtype probe: call with a full wave; uniform result. fp32 storage: bit14 is a
// mantissa bit (~50% set over 64 samples). bf16 storage: bit14 = exp MSB of the
// low bf16 (|x|>=2) -> 0 hits for ~N(0,0.05) weights.
__device__ __forceinline__ bool detect_f32(const void* etab) {
  u32 w = ((const u32*)etab)[threadIdx.x & 63];
  u64 m = __ballot((w & 0x4000u) != 0);
  return __popcll(m) >= 16;
}
__device__ __forceinline__ float ldf(const void* p, int i, bool f32m) {
  return f32m ? ((const float*)p)[i] : b2f(((const u16*)p)[i]);
}

// ---------------- k_embed_xw: sentinel-init hstep + embeddings + x@W (+b) ----------------
// grid 256 = 64 rowgroups x {dir,colhalf}; 8 rows, 512 cols per block.
__global__ __launch_bounds__(256) void k_embed_xw(
    const int* __restrict__ toks, const int* __restrict__ wrds,
    const void* __restrict__ etab, const void* __restrict__ wtab,
    const void* __restrict__ Wf, const void* __restrict__ bf_,
    const void* __restrict__ Wb, const void* __restrict__ bb_,
    float* __restrict__ ws)
{
  __shared__ float xs[8][256];
  const int tid = threadIdx.x, bx = blockIdx.x;
  const int rg = bx >> 2, part = bx & 3, dir = part >> 1, ch = part & 1;
  // sentinel-init hstep (131072 u64 across 256 blocks). L2-bypassing atomic
  // stores so no dirty sentinel line can be written back to L3 late.
  {
    u64* hz = (u64*)(ws + HF_O) + (bx * 256 + tid) * 2;
    astore64(hz, SENT64); astore64(hz + 1, SENT64);
  }
  const bool f32m = detect_f32(etab);
  for (int rr = 0; rr < 8; rr++) {
    const int row = rg * 8 + rr;
    const int id = toks[row], wid = wrds[row];
    xs[rr][tid] = (tid < 128) ? ldf(etab, id * 128 + tid, f32m)
                              : ldf(wtab, wid * 128 + (tid - 128), f32m);
  }
  __syncthreads();
  const void* W = dir ? Wb : Wf;
  const void* bb = dir ? bb_ : bf_;
  const int c0 = ch * 512 + 2 * tid;
  float acc[8][2];
#pragma unroll
  for (int rr = 0; rr < 8; rr++) { acc[rr][0] = 0.f; acc[rr][1] = 0.f; }
  if (f32m) {
    const float2* W2 = (const float2*)W;
    for (int k = 0; k < 256; k++) {
      const float2 w = W2[k * 512 + (c0 >> 1)];
#pragma unroll
      for (int rr = 0; rr < 8; rr++) {
        const float x = xs[rr][k];
        acc[rr][0] = fmaf(x, w.x, acc[rr][0]);
        acc[rr][1] = fmaf(x, w.y, acc[rr][1]);
      }
    }
  } else {
    const u32* W2 = (const u32*)W;
    for (int k = 0; k < 256; k++) {
      const u32 v = W2[k * 512 + (c0 >> 1)];
      const float wx = b2f(v & 0xffff), wy = b2f(v >> 16);
#pragma unroll
      for (int rr = 0; rr < 8; rr++) {
        const float x = xs[rr][k];
        acc[rr][0] = fmaf(x, wx, acc[rr][0]);
        acc[rr][1] = fmaf(x, wy, acc[rr][1]);
      }
    }
  }
  const float b0 = ldf(bb, c0, f32m), b1 = ldf(bb, c0 + 1, f32m);
  float* xwb = ws + (dir ? XW_B : XW_F);
#pragma unroll
  for (int rr = 0; rr < 8; rr++) {
    const int row = rg * 8 + rr;
    float2 o = make_float2(acc[rr][0] + b0, acc[rr][1] + b1);
    *(float2*)(xwb + row * 1024 + c0) = o;
  }
}

// ---------------- k_lstm: dual-direction interleaved recurrence ----------------
// 16 WGs, each owns hidden units [w*16,w*16+16) of BOTH directions.
// U fragments in VGPRs; h exchanged via L3 (agent atomics, u64-packed batches,
// qNaN sentinel). Poll loads issued ~one phase before the check, so the L3
// round-trip hides behind the other direction's compute.
__global__ __launch_bounds__(256, 1) void k_lstm(
    const int* __restrict__ toks,
    const void* __restrict__ Uf_raw, const void* __restrict__ Ub_raw,
    const void* __restrict__ etab, float* __restrict__ ws)
{
  __shared__ float2 hsh0[256], hsh1[256];
  __shared__ float psum0[8][128], psum1[8][128];
  __shared__ float zsh0[128], zsh1[128];
  __shared__ int msk[512];
  const int tid = threadIdx.x;
  const int w = blockIdx.x, base = w * 16;
  const int q = tid & 31, ksec = tid >> 5, k0 = ksec * 32;
  u64* h0 = (u64*)(ws + HF_O);
  u64* h1 = (u64*)(ws + HB_O);
  const float* xw0 = ws + XW_F;
  const float* xw1 = ws + XW_B;
  const bool f32m = detect_f32(etab);

  // U fragments: local cols lc0=2q, lc0+1 (of 64); global col = gate*256+base+j
  const int lc0 = 2 * q;
  const int gc0 = (lc0 >> 4) * 256 + base + (lc0 & 15);
  float2 us0[32], us1[32];
  if (f32m) {
    const float* U0 = (const float*)Uf_raw;
    const float* U1 = (const float*)Ub_raw;
#pragma unroll
    for (int j = 0; j < 32; j++) {
      us0[j] = *(const float2*)(U0 + (k0 + j) * 1024 + gc0);
      us1[j] = *(const float2*)(U1 + (k0 + j) * 1024 + gc0);
    }
  } else {
    const u32* U0 = (const u32*)Uf_raw;
    const u32* U1 = (const u32*)Ub_raw;
#pragma unroll
    for (int j = 0; j < 32; j++) {
      u32 v0 = U0[((k0 + j) * 1024 + gc0) >> 1];
      u32 v1 = U1[((k0 + j) * 1024 + gc0) >> 1];
      us0[j] = make_float2(b2f(v0 & 0xffff), b2f(v0 >> 16));
      us1[j] = make_float2(b2f(v1 & 0xffff), b2f(v1 >> 16));
    }
  }
  // reduce role (tid<128): lc = tid>>1, b = tid&1
  const int rlc = tid >> 1, rbb = tid & 1;
  const int rgc = (rlc >> 4) * 256 + base + (rlc & 15);
  // gate role (tid<32): unit gj, batch gb
  const int gj = tid & 15, gb = (tid >> 4) & 1;
  const bool own = (tid >= base) && (tid < base + 16);

  msk[tid] = toks[tid]; msk[tid + 256] = toks[tid + 256];
  hsh0[tid] = make_float2(0.f, 0.f);
  hsh1[tid] = make_float2(0.f, 0.f);
  float c0Reg = 0.f, h0Reg = 0.f, c1Reg = 0.f, h1Reg = 0.f;
  float xw0reg = xw0[rbb * 262144 + 0 * 1024 + rgc];        // t=0
  float xw1reg = xw1[rbb * 262144 + 255 * 1024 + rgc];      // t=255
  __syncthreads();

  for (int s = 0; s < LSEQ; s++) {
    // P1: issue poll loads for dir1 h[s-1] (checked at C)
    u64 v1 = 0;
    if (s > 0 && !own) v1 = aload64(&h1[(s - 1) * 256 + tid]);
    // A: partials dir0 (hsh0 = dir0 h[s-1])
    {
      float4 a = make_float4(0.f, 0.f, 0.f, 0.f);
#pragma unroll
      for (int j = 0; j < 32; j++) {
        const float2 h = hsh0[k0 + j];
        const float2 u = us0[j];
        a.x = fmaf(h.x, u.x, a.x); a.y = fmaf(h.y, u.x, a.y);
        a.z = fmaf(h.x, u.y, a.z); a.w = fmaf(h.y, u.y, a.w);
      }
      *(float4*)&psum0[ksec][4 * q] = a;
    }
    __syncthreads();                               // B1
    if (tid < 128) {
      float z = xw0reg;
#pragma unroll
      for (int ks = 0; ks < 8; ks++) z += psum0[ks][tid];
      zsh0[tid] = z;
      const int t2 = (s < 255) ? s + 1 : 255;
      xw0reg = xw0[rbb * 262144 + t2 * 1024 + rgc];
    }
    __syncthreads();                               // B2
    // C: gates dir0 + consume dir1 poll
    if (tid < 32) {
      const float zi = zsh0[gj * 2 + gb],        zf = zsh0[(16 + gj) * 2 + gb];
      const float zg = zsh0[(32 + gj) * 2 + gb], zo = zsh0[(48 + gj) * 2 + gb];
      const float cn = sigm(zf) * c0Reg + sigm(zi) * tanh_fast(zg);
      const float hn = sigm(zo) * tanh_fast(cn);
      if (msk[gb * 256 + s] != 0) { c0Reg = cn; h0Reg = hn; }
      const float hp = __shfl_xor(h0Reg, 16);
      if (tid < 16) {
        const float2 fv = make_float2(h0Reg, hp);
        hsh0[base + tid] = fv;
        u64 pv; __builtin_memcpy(&pv, &fv, 8);
        astore64(&h0[s * 256 + base + tid], pv);
      }
    }
    if (s > 0 && !own) {
      while (v1 == SENT64) v1 = aload64(&h1[(s - 1) * 256 + tid]);
      float2 hv; __builtin_memcpy(&hv, &v1, 8);
      hsh1[tid] = hv;
    }
    __syncthreads();                               // B3
    // P2: issue poll loads for dir0 h[s] (checked at F)
    u64 v0 = 0;
    if (s < 255 && !own) v0 = aload64(&h0[s * 256 + tid]);
    // D: partials dir1 (hsh1 = dir1 h[s-1])
    {
      float4 a = make_float4(0.f, 0.f, 0.f, 0.f);
#pragma unroll
      for (int j = 0; j < 32; j++) {
        const float2 h = hsh1[k0 + j];
        const float2 u = us1[j];
        a.x = fmaf(h.x, u.x, a.x); a.y = fmaf(h.y, u.x, a.y);
        a.z = fmaf(h.x, u.y, a.z); a.w = fmaf(h.y, u.y, a.w);
      }
      *(float4*)&psum1[ksec][4 * q] = a;
    }
    __syncthreads();                               // B4
    if (tid < 128) {
      float z = xw1reg;
#pragma unroll
      for (int ks = 0; ks < 8; ks++) z += psum1[ks][tid];
      zsh1[tid] = z;
      const int t2 = (s < 255) ? 254 - s : 0;
      xw1reg = xw1[rbb * 262144 + t2 * 1024 + rgc];
    }
    __syncthreads();                               // B5
    // F: gates dir1 + consume dir0 poll
    if (tid < 32) {
      const float zi = zsh1[gj * 2 + gb],        zf = zsh1[(16 + gj) * 2 + gb];
      const float zg = zsh1[(32 + gj) * 2 + gb], zo = zsh1[(48 + gj) * 2 + gb];
      const float cn = sigm(zf) * c1Reg + sigm(zi) * tanh_fast(zg);
      const float hn = sigm(zo) * tanh_fast(cn);
      if (msk[gb * 256 + (255 - s)] != 0) { c1Reg = cn; h1Reg = hn; }
      const float hp = __shfl_xor(h1Reg, 16);
      if (tid < 16) {
        const float2 fv = make_float2(h1Reg, hp);
        hsh1[base + tid] = fv;
        u64 pv; __builtin_memcpy(&pv, &fv, 8);
        astore64(&h1[s * 256 + base + tid], pv);
      }
    }
    if (s < 255 && !own) {
      while (v0 == SENT64) v0 = aload64(&h0[s * 256 + tid]);
      float2 hv; __builtin_memcpy(&hv, &v0, 8);
      hsh0[tid] = hv;
    }
    __syncthreads();                               // B6
  }
}

// ---------------- k_uvpq: fused relu(enc@W+b) -> (a,q) = @Wuv -> P,Q = @Wc ----------------
// grid (64 rowgroups, 3 heads), 8 rows per block.
struct HeadPack { const void* p[24]; };  // per head: uW,ub,vW,vb,uvW,uvb,cW,cb

__global__ __launch_bounds__(256) void k_uvpq(
    HeadPack pk, const void* __restrict__ etab, float* __restrict__ ws)
{
  __shared__ float encs_t[512][8];     // [h][row]
  __shared__ float usv_t[2][128][8];   // [u/v][col][row]
  __shared__ float apq[2][8][128];     // [a/q][row][col]
  __shared__ float wc[3072];
  const int tid = threadIdx.x, rgp = blockIdx.x, hd = blockIdx.y;
  const bool f32m = detect_f32(etab);
  const void* uW  = pk.p[hd * 8 + 0]; const void* ub  = pk.p[hd * 8 + 1];
  const void* vW  = pk.p[hd * 8 + 2]; const void* vb  = pk.p[hd * 8 + 3];
  const void* uvW = pk.p[hd * 8 + 4]; const void* uvb = pk.p[hd * 8 + 5];
  const void* cW  = pk.p[hd * 8 + 6];
  const int nout = (hd == 0) ? 1 : 24;
  for (int i = tid; i < 128 * nout; i += 256) wc[i] = ldf(cW, i, f32m);
  // load enc (transposed): encs_t[h][rr]
  for (int i = tid; i < 4096; i += 256) {
    const int h = i >> 3, rr = i & 7;
    const int row = rgp * 8 + rr, b = row >> 8, t = row & 255;
    encs_t[h][rr] = (h < 256)
        ? ws[HF_O + t * 512 + h * 2 + b]
        : ws[HB_O + (255 - t) * 512 + (h - 256) * 2 + b];
  }
  __syncthreads();
  // phase 1: mat = tid>>7 (0=u,1=v), cs = tid&127
  {
    const int mat = tid >> 7, cs = tid & 127;
    const void* W = mat ? vW : uW;
    const float bias = ldf(mat ? vb : ub, cs, f32m);
    float acc[8];
#pragma unroll
    for (int rr = 0; rr < 8; rr++) acc[rr] = 0.f;
    if (f32m) {
      const float* Wf = (const float*)W;
      for (int k = 0; k < 512; k++) {
        const float wv = Wf[k * 128 + cs];
        const float4 e0 = *(const float4*)&encs_t[k][0];
        const float4 e1 = *(const float4*)&encs_t[k][4];
        acc[0] = fmaf(e0.x, wv, acc[0]); acc[1] = fmaf(e0.y, wv, acc[1]);
        acc[2] = fmaf(e0.z, wv, acc[2]); acc[3] = fmaf(e0.w, wv, acc[3]);
        acc[4] = fmaf(e1.x, wv, acc[4]); acc[5] = fmaf(e1.y, wv, acc[5]);
        acc[6] = fmaf(e1.z, wv, acc[6]); acc[7] = fmaf(e1.w, wv, acc[7]);
      }
    } else {
      const u16* Wf = (const u16*)W;
      for (int k = 0; k < 512; k++) {
        const float wv = b2f(Wf[k * 128 + cs]);
        const float4 e0 = *(const float4*)&encs_t[k][0];
        const float4 e1 = *(const float4*)&encs_t[k][4];
        acc[0] = fmaf(e0.x, wv, acc[0]); acc[1] = fmaf(e0.y, wv, acc[1]);
        acc[2] = fmaf(e0.z, wv, acc[2]); acc[3] = fmaf(e0.w, wv, acc[3]);
        acc[4] = fmaf(e1.x, wv, acc[4]); acc[5] = fmaf(e1.y, wv, acc[5]);
        acc[6] = fmaf(e1.z, wv, acc[6]); acc[7] = fmaf(e1.w, wv, acc[7]);
      }
    }
#pragma unroll
    for (int rr = 0; rr < 8; rr++)
      usv_t[mat][cs][rr] = fmaxf(acc[rr] + bias, 0.f);
  }
  __syncthreads();
  // phase 2: half = tid>>7 (0: a = u@Wuv[0:128]+buv, 1: q = v@Wuv[128:256])
  {
    const int half = tid >> 7, col = tid & 127;
    float acc[8];
#pragma unroll
    for (int rr = 0; rr < 8; rr++) acc[rr] = 0.f;
    if (f32m) {
      const float* Wf = (const float*)uvW;
      for (int k = 0; k < 128; k++) {
        const float wv = Wf[(half * 128 + k) * 128 + col];
        const float4 e0 = *(const float4*)&usv_t[half][k][0];
        const float4 e1 = *(const float4*)&usv_t[half][k][4];
        acc[0] = fmaf(e0.x, wv, acc[0]); acc[1] = fmaf(e0.y, wv, acc[1]);
        acc[2] = fmaf(e0.z, wv, acc[2]); acc[3] = fmaf(e0.w, wv, acc[3]);
        acc[4] = fmaf(e1.x, wv, acc[4]); acc[5] = fmaf(e1.y, wv, acc[5]);
        acc[6] = fmaf(e1.z, wv, acc[6]); acc[7] = fmaf(e1.w, wv, acc[7]);
      }
    } else {
      const u16* Wf = (const u16*)uvW;
      for (int k = 0; k < 128; k++) {
        const float wv = b2f(Wf[(half * 128 + k) * 128 + col]);
        const float4 e0 = *(const float4*)&usv_t[half][k][0];
        const float4 e1 = *(const float4*)&usv_t[half][k][4];
        acc[0] = fmaf(e0.x, wv, acc[0]); acc[1] = fmaf(e0.y, wv, acc[1]);
        acc[2] = fmaf(e0.z, wv, acc[2]); acc[3] = fmaf(e0.w, wv, acc[3]);
        acc[4] = fmaf(e1.x, wv, acc[4]); acc[5] = fmaf(e1.y, wv, acc[5]);
        acc[6] = fmaf(e1.z, wv, acc[6]); acc[7] = fmaf(e1.w, wv, acc[7]);
      }
    }
    const float bv = (half == 0) ? ldf(uvb, col, f32m) : 0.f;
#pragma unroll
    for (int rr = 0; rr < 8; rr++)
      apq[half][rr][col] = acc[rr] + bv;
  }
  __syncthreads();
  // phase 3: cls
  if (hd == 0) {
    if (tid < 16) {
      const int rr = tid >> 1, aq = tid & 1;
      float acc = 0.f;
      for (int e = 0; e < 128; e++) acc = fmaf(apq[aq][rr][e], wc[e], acc);
      const int row = rgp * 8 + rr;
      ws[(aq ? QEH_O : PEH_O) + row] = acc;
    }
  } else {
    const int PO = (hd == 1) ? PHH_O : PTT_O;
    const int QO = (hd == 1) ? QHH_O : QTT_O;
    for (int it = 0; it < 2; it++) {
      if (tid < 192) {
        const int task = it * 192 + tid;
        const int rr = task / 48, r2 = task % 48;
        const int aq = r2 / 24, o = r2 % 24;
        float acc = 0.f;
        for (int e = 0; e < 128; e++) acc = fmaf(apq[aq][rr][e], wc[e * 24 + o], acc);
        const int row = rgp * 8 + rr;
        ws[(aq ? QO : PO) + row * 24 + o] = acc;
      }
    }
  }
}

// ---------------- k_out: out[b,i,j] = act(P[b,j] + Q[b,i] + bc) ----------------
__global__ __launch_bounds__(256) void k_out(
    const void* __restrict__ bceh, const void* __restrict__ bchh,
    const void* __restrict__ bctt, const void* __restrict__ etab,
    const float* __restrict__ ws, void* __restrict__ outv)
{
  __shared__ float qh[24], qt[24];
  __shared__ float qe_s;
  __shared__ u32 sh[3072], st[3072];
  const bool f32m = detect_f32(etab);
  const int bi = blockIdx.x, b = bi >> 8, i = bi & 255;
  const int j = threadIdx.x;
  if (j < 24)       qh[j] = ws[QHH_O + (b * 256 + i) * 24 + j] + ldf(bchh, j, f32m);
  else if (j < 48)  qt[j - 24] = ws[QTT_O + (b * 256 + i) * 24 + (j - 24)] + ldf(bctt, j - 24, f32m);
  else if (j == 48) qe_s = ws[QEH_O + b * 256 + i] + ldf(bceh, 0, f32m);
  __syncthreads();
  {
    float v = ws[PEH_O + b * 256 + j] + qe_s;
    v = 1.f / (1.f + __expf(-v));
    if (f32m) ((float*)outv)[(b * 256 + i) * 256 + j] = v;
    else      ((u16*)outv)[(b * 256 + i) * 256 + j] = f2b(v);
  }
  float p[24];
  {
    const float* pp = ws + PHH_O + (b * 256 + j) * 24;
    float mx = -1e30f;
#pragma unroll
    for (int o = 0; o < 24; o++) { p[o] = pp[o] + qh[o]; mx = fmaxf(mx, p[o]); }
    float ssum = 0.f;
#pragma unroll
    for (int o = 0; o < 24; o++) { p[o] = __expf(p[o] - mx); ssum += p[o]; }
    const float inv = 1.f / ssum;
    if (f32m) {
      float* dst = (float*)outv + 131072 + (size_t)(bi * 256 + j) * 24;
#pragma unroll
      for (int m = 0; m < 6; m++)
        ((float4*)dst)[m] = make_float4(p[4*m]*inv, p[4*m+1]*inv, p[4*m+2]*inv, p[4*m+3]*inv);
    } else {
#pragma unroll
      for (int m = 0; m < 12; m++)
        sh[j * 12 + m] = ((u32)f2b(p[2*m+1] * inv) << 16) | (u32)f2b(p[2*m] * inv);
    }
  }
  {
    const float* pp = ws + PTT_O + (b * 256 + j) * 24;
    float mx = -1e30f;
#pragma unroll
    for (int o = 0; o < 24; o++) { p[o] = pp[o] + qt[o]; mx = fmaxf(mx, p[o]); }
    float ssum = 0.f;
#pragma unroll
    for (int o = 0; o < 24; o++) { p[o] = __expf(p[o] - mx); ssum += p[o]; }
    const float inv = 1.f / ssum;
    if (f32m) {
      float* dst = (float*)outv + 3276800 + (size_t)(bi * 256 + j) * 24;
#pragma unroll
      for (int m = 0; m < 6; m++)
        ((float4*)dst)[m] = make_float4(p[4*m]*inv, p[4*m+1]*inv, p[4*m+2]*inv, p[4*m+3]*inv);
    } else {
#pragma unroll
      for (int m = 0; m < 12; m++)
        st[j * 12 + m] = ((u32)f2b(p[2*m+1] * inv) << 16) | (u32)f2b(p[2*m] * inv);
    }
  }
  __syncthreads();
  if (!f32m) {
    u32* outu = (u32*)outv;
    const int baseH = 65536 + bi * 3072;     // eh = elems [0,131072)
    const int baseT = 1638400 + bi * 3072;   // tt starts at elem 3276800
#pragma unroll
    for (int m = 0; m < 12; m++) {
      outu[baseH + j + 256 * m] = sh[j + 256 * m];
      outu[baseT + j + 256 * m] = st[j + 256 * m];
    }
  }
}

extern "C" void kernel_launch(void* const* d_in, const int* in_sizes, int n_in,
                              void* d_out, int out_size, void* d_ws, size_t ws_size,
                              hipStream_t stream) {
  const int* toks = (const int*)d_in[0];
  const int* wrds = (const int*)d_in[1];
  float* ws = (float*)d_ws;

  k_embed_xw<<<dim3(256), dim3(256), 0, stream>>>(
      toks, wrds, d_in[3], d_in[4], d_in[5], d_in[7], d_in[8], d_in[10], ws);
  k_lstm<<<dim3(16), dim3(256), 0, stream>>>(toks, d_in[6], d_in[9], d_in[3], ws);
  HeadPack pk;
  for (int h = 0; h < 3; h++)
    for (int a = 0; a < 8; a++)
      pk.p[h * 8 + a] = d_in[11 + h * 8 + a];
  k_uvpq<<<dim3(64, 3), dim3(256), 0, stream>>>(pk, d_in[3], ws);
  k_out<<<dim3(512), dim3(256), 0, stream>>>(
      d_in[18], d_in[26], d_in[34], d_in[3], ws, d_out);
}